// Round 2
// baseline (1041.380 us; speedup 1.0000x reference)
//
#include <hip/hip_runtime.h>
#include <hip/hip_bf16.h>
#include <float.h>
#include <math.h>

// Decoder3: ragged maxpool -> a; then T=8 sequential GRU-decoder steps.
// B=128 T=8 E=52 S=2048 R=512 L=4, VOCAB=512.
// Outputs (float32, concat): dec_output[T*B] | dec_prob[T*B*L] | disc_input[T*B*L] | kl_input[T*B]

#define B_ 128
#define T_ 8
#define E_ 52
#define S_ 2048
#define R_ 512
#define L_ 4
#define GR_ 1536   // 3R
#define KX_ 104    // 2E
#define NCHUNK 16
#define SCHUNK (S_ / NCHUNK)   // 128

__device__ __constant__ int c_remap[4] = {175, 176, 44, 173};

// ---------------- Phase 1: ragged max-pool (partial, chunked over S) ----------------
// grid (NCHUNK, B), block 128; thread t owns float4 at r=4t. Coalesced 2KB/row.
__global__ void k_maxpool(const float* __restrict__ enc, const int* __restrict__ enc_len,
                          float4* __restrict__ partial) {
    int c = blockIdx.x;
    int b = blockIdx.y;
    int t = threadIdx.x;  // 0..127
    int len = enc_len[b];
    int s0 = c * SCHUNK;
    int s1 = min(s0 + SCHUNK, len);
    float4 m = make_float4(-FLT_MAX, -FLT_MAX, -FLT_MAX, -FLT_MAX);
    const float4* base = (const float4*)(enc + (size_t)b * S_ * R_);
    for (int s = s0; s < s1; ++s) {
        float4 v = base[(size_t)s * (R_ / 4) + t];
        m.x = fmaxf(m.x, v.x);
        m.y = fmaxf(m.y, v.y);
        m.z = fmaxf(m.z, v.z);
        m.w = fmaxf(m.w, v.w);
    }
    partial[((size_t)b * NCHUNK + c) * (R_ / 4) + t] = m;
}

// ---------------- Phase 1b: reduce partials + a = code_pool @ W_fc.T ----------------
// grid B, block 256
__global__ void k_pool_a(const float* __restrict__ partial, const float* __restrict__ W_fc,
                         float* __restrict__ a_out) {
    int b = blockIdx.x;
    int tid = threadIdx.x;
    __shared__ float cp[R_];
    for (int r = tid; r < R_; r += 256) {
        float m = -FLT_MAX;
        const float* p = partial + (size_t)b * NCHUNK * R_ + r;
        #pragma unroll
        for (int c = 0; c < NCHUNK; ++c) m = fmaxf(m, p[c * R_]);
        cp[r] = m;
    }
    __syncthreads();
    float p0 = 0.f, p1 = 0.f, p2 = 0.f, p3 = 0.f;
    for (int r = tid; r < R_; r += 256) {
        float v = cp[r];
        p0 += v * W_fc[0 * R_ + r];
        p1 += v * W_fc[1 * R_ + r];
        p2 += v * W_fc[2 * R_ + r];
        p3 += v * W_fc[3 * R_ + r];
    }
    #pragma unroll
    for (int off = 32; off > 0; off >>= 1) {
        p0 += __shfl_down(p0, off);
        p1 += __shfl_down(p1, off);
        p2 += __shfl_down(p2, off);
        p3 += __shfl_down(p3, off);
    }
    __shared__ float red[4][4];
    int wv = tid >> 6, lane = tid & 63;
    if (lane == 0) { red[wv][0] = p0; red[wv][1] = p1; red[wv][2] = p2; red[wv][3] = p3; }
    __syncthreads();
    if (tid < 4) {
        a_out[b * L_ + tid] = red[0][tid] + red[1][tid] + red[2][tid] + red[3][tid];
    }
}

// ---------------- One-time weight transpose: W[n,k] -> WT[k,n] ----------------
__global__ void k_transpose(const float* __restrict__ in, float* __restrict__ out, int n, int k) {
    __shared__ float tile[32][33];
    int j0 = blockIdx.x * 32;  // k dim
    int i0 = blockIdx.y * 32;  // n dim
    int tx = threadIdx.x, ty = threadIdx.y;  // 32, 8
    #pragma unroll
    for (int dy = 0; dy < 32; dy += 8) {
        int i = i0 + ty + dy, j = j0 + tx;
        if (i < n && j < k) tile[ty + dy][tx] = in[(size_t)i * k + j];
    }
    __syncthreads();
    #pragma unroll
    for (int dy = 0; dy < 32; dy += 8) {
        int j = j0 + ty + dy, i = i0 + tx;
        if (j < k && i < n) out[(size_t)j * n + i] = tile[tx][ty + dy];
    }
}

// ---------------- Per-step head: bmi_h, argmax, remap, outputs, xcat ----------------
// grid B, block 128
__global__ void k_step_pre(const float* __restrict__ h, const float* __restrict__ W_reg,
                           const float* __restrict__ b_reg, const float* __restrict__ a_vec,
                           const float* __restrict__ featEmbed, const float* __restrict__ labelsEmbed,
                           const int* __restrict__ mask, const float* __restrict__ emb_table,
                           int t, float* __restrict__ xcat, float* __restrict__ out) {
    int b = blockIdx.x;
    int tid = threadIdx.x;  // 128
    float p0 = 0.f, p1 = 0.f, p2 = 0.f, p3 = 0.f;
    const float* hb = h + b * R_;
    for (int r = tid; r < R_; r += 128) {
        float v = hb[r];
        p0 += v * W_reg[0 * R_ + r];
        p1 += v * W_reg[1 * R_ + r];
        p2 += v * W_reg[2 * R_ + r];
        p3 += v * W_reg[3 * R_ + r];
    }
    #pragma unroll
    for (int off = 32; off > 0; off >>= 1) {
        p0 += __shfl_down(p0, off);
        p1 += __shfl_down(p1, off);
        p2 += __shfl_down(p2, off);
        p3 += __shfl_down(p3, off);
    }
    __shared__ float red[2][4];
    __shared__ int sh_ld;
    int wv = tid >> 6, lane = tid & 63;
    if (lane == 0) { red[wv][0] = p0; red[wv][1] = p1; red[wv][2] = p2; red[wv][3] = p3; }
    __syncthreads();
    if (tid == 0) {
        float bh[4], pr[4];
        #pragma unroll
        for (int l = 0; l < 4; ++l) {
            bh[l] = red[0][l] + red[1][l] + b_reg[l] + a_vec[b * 4 + l];
            pr[l] = 1.0f / (1.0f + expf(-bh[l]));
        }
        int best = 0;
        float bv = pr[0];
        #pragma unroll
        for (int l = 1; l < 4; ++l) {
            if (pr[l] > bv) { bv = pr[l]; best = l; }  // first-max, matches np argmax
        }
        int ld = c_remap[best];
        sh_ld = ld;
        out[t * B_ + b] = (float)best;
        #pragma unroll
        for (int l = 0; l < 4; ++l) {
            out[1024 + (t * B_ + b) * 4 + l] = pr[l];
            out[5120 + (t * B_ + b) * 4 + l] = bh[l];
        }
        out[9216 + t * B_ + b] = (float)ld;
    }
    __syncthreads();
    if (tid < E_) {
        xcat[b * KX_ + tid] = featEmbed[b * (T_ * E_) + t * E_ + tid];
    } else if (tid >= 64 && tid < 64 + E_) {
        int e = tid - 64;
        int m = mask[b * T_ + t];
        float v = m ? labelsEmbed[b * (T_ * E_) + t * E_ + e] : emb_table[sh_ld * E_ + e];
        xcat[b * KX_ + E_ + e] = v;
    }
}

// ---------------- Per-step GRU cell (fused dual-GEMM + gates) ----------------
// grid (R/64, B/4), block 256: wave -> batch, lane -> output unit rr.
__global__ void __launch_bounds__(256) k_step_gru(
        const float* __restrict__ xcat, const float* __restrict__ h,
        const float* __restrict__ WihT, const float* __restrict__ WhhT,
        const float* __restrict__ b_ih, const float* __restrict__ b_hh,
        float* __restrict__ h_out) {
    int lane = threadIdx.x & 63;
    int wv = threadIdx.x >> 6;
    int rr = blockIdx.x * 64 + lane;
    int b = blockIdx.y * 4 + wv;
    float air = 0.f, aiz = 0.f, ain = 0.f, ahr = 0.f, ahz = 0.f, ahn = 0.f;
    const float* xr = xcat + b * KX_;
    const float* wp = WihT + rr;
    #pragma unroll 4
    for (int k = 0; k < KX_; ++k) {
        float x = xr[k];
        air = fmaf(x, wp[0], air);
        aiz = fmaf(x, wp[512], aiz);
        ain = fmaf(x, wp[1024], ain);
        wp += GR_;
    }
    const float* hrow = h + b * R_;
    wp = WhhT + rr;
    #pragma unroll 4
    for (int k = 0; k < R_; ++k) {
        float hv = hrow[k];
        ahr = fmaf(hv, wp[0], ahr);
        ahz = fmaf(hv, wp[512], ahz);
        ahn = fmaf(hv, wp[1024], ahn);
        wp += GR_;
    }
    float r = 1.0f / (1.0f + expf(-(air + b_ih[rr] + ahr + b_hh[rr])));
    float z = 1.0f / (1.0f + expf(-(aiz + b_ih[rr + 512] + ahz + b_hh[rr + 512])));
    float n = tanhf(ain + b_ih[rr + 1024] + r * (ahn + b_hh[rr + 1024]));
    h_out[b * R_ + rr] = (1.0f - z) * n + z * hrow[rr];
}

extern "C" void kernel_launch(void* const* d_in, const int* in_sizes, int n_in,
                              void* d_out, int out_size, void* d_ws, size_t ws_size,
                              hipStream_t stream) {
    const float* featEmbed   = (const float*)d_in[0];
    const float* labelsEmbed = (const float*)d_in[1];
    const float* enc         = (const float*)d_in[2];
    const float* h_n         = (const float*)d_in[3];
    const int*   mask        = (const int*)d_in[4];
    const int*   enc_len     = (const int*)d_in[5];
    const float* emb_table   = (const float*)d_in[6];
    const float* W_fc        = (const float*)d_in[7];
    const float* W_reg       = (const float*)d_in[8];
    const float* b_reg       = (const float*)d_in[9];
    const float* W_ih        = (const float*)d_in[10];
    const float* W_hh        = (const float*)d_in[11];
    const float* b_ih        = (const float*)d_in[12];
    const float* b_hh        = (const float*)d_in[13];
    float* out = (float*)d_out;

    // workspace layout (floats); total ~2.14M floats = ~8.6 MB
    float* ws      = (float*)d_ws;
    float* partial = ws;                          // B*NCHUNK*R = 1048576
    float* WihT    = partial + B_ * NCHUNK * R_;  // KX*GR = 159744
    float* WhhT    = WihT + KX_ * GR_;            // R*GR  = 786432
    float* xcat    = WhhT + R_ * GR_;             // B*KX  = 13312
    float* h0      = xcat + B_ * KX_;             // B*R   = 65536
    float* h1      = h0 + B_ * R_;                // B*R   = 65536
    float* a_vec   = h1 + B_ * R_;                // B*L   = 512

    k_maxpool<<<dim3(NCHUNK, B_), 128, 0, stream>>>(enc, enc_len, (float4*)partial);
    k_pool_a<<<B_, 256, 0, stream>>>(partial, W_fc, a_vec);
    k_transpose<<<dim3((KX_ + 31) / 32, (GR_ + 31) / 32), dim3(32, 8), 0, stream>>>(W_ih, WihT, GR_, KX_);
    k_transpose<<<dim3((R_ + 31) / 32, (GR_ + 31) / 32), dim3(32, 8), 0, stream>>>(W_hh, WhhT, GR_, R_);

    const float* hcur = h_n;
    for (int t = 0; t < T_; ++t) {
        float* hnext = (t & 1) ? h1 : h0;
        k_step_pre<<<B_, 128, 0, stream>>>(hcur, W_reg, b_reg, a_vec, featEmbed, labelsEmbed,
                                           mask, emb_table, t, xcat, out);
        k_step_gru<<<dim3(R_ / 64, B_ / 4), 256, 0, stream>>>(xcat, hcur, WihT, WhhT,
                                                              b_ih, b_hh, hnext);
        hcur = hnext;
    }
}

// Round 3
// 874.318 us; speedup vs baseline: 1.1911x; 1.1911x over previous
//
#include <hip/hip_runtime.h>
#include <hip/hip_bf16.h>
#include <float.h>
#include <math.h>

// Decoder3: ragged maxpool -> a; then T=8 sequential fused GRU-decoder steps.
// B=128 T=8 E=52 S=2048 R=512 L=4.
// Outputs (f32, concat): dec_output[T*B] | dec_prob[T*B*L] | disc_input[T*B*L] | kl_input[T*B]

#define B_ 128
#define T_ 8
#define E_ 52
#define S_ 2048
#define R_ 512
#define L_ 4
#define GR_ 1536   // 3R
#define KX_ 104    // 2E
#define NCHUNK 16
#define SCHUNK (S_ / NCHUNK)   // 128
#define KQ_ 154    // 616/4 merged-K quarter

__device__ __constant__ int c_remap[4] = {175, 176, 44, 173};

__device__ __forceinline__ float sigmoidf(float x) { return 1.0f / (1.0f + expf(-x)); }

// ---------------- Phase 1: ragged max-pool (partial, chunked over S) ----------------
__global__ void k_maxpool(const float* __restrict__ enc, const int* __restrict__ enc_len,
                          float4* __restrict__ partial) {
    int c = blockIdx.x;
    int b = blockIdx.y;
    int t = threadIdx.x;  // 0..127
    int len = enc_len[b];
    int s0 = c * SCHUNK;
    int s1 = min(s0 + SCHUNK, len);
    float4 m = make_float4(-FLT_MAX, -FLT_MAX, -FLT_MAX, -FLT_MAX);
    const float4* base = (const float4*)(enc + (size_t)b * S_ * R_);
    for (int s = s0; s < s1; ++s) {
        float4 v = base[(size_t)s * (R_ / 4) + t];
        m.x = fmaxf(m.x, v.x);
        m.y = fmaxf(m.y, v.y);
        m.z = fmaxf(m.z, v.z);
        m.w = fmaxf(m.w, v.w);
    }
    partial[((size_t)b * NCHUNK + c) * (R_ / 4) + t] = m;
}

// ---------------- Phase 1b: reduce partials + a = code_pool @ W_fc.T ----------------
__global__ void k_pool_a(const float* __restrict__ partial, const float* __restrict__ W_fc,
                         float* __restrict__ a_out) {
    int b = blockIdx.x;
    int tid = threadIdx.x;
    __shared__ float cp[R_];
    for (int r = tid; r < R_; r += 256) {
        float m = -FLT_MAX;
        const float* p = partial + (size_t)b * NCHUNK * R_ + r;
        #pragma unroll
        for (int c = 0; c < NCHUNK; ++c) m = fmaxf(m, p[c * R_]);
        cp[r] = m;
    }
    __syncthreads();
    float p0 = 0.f, p1 = 0.f, p2 = 0.f, p3 = 0.f;
    for (int r = tid; r < R_; r += 256) {
        float v = cp[r];
        p0 = fmaf(v, W_fc[0 * R_ + r], p0);
        p1 = fmaf(v, W_fc[1 * R_ + r], p1);
        p2 = fmaf(v, W_fc[2 * R_ + r], p2);
        p3 = fmaf(v, W_fc[3 * R_ + r], p3);
    }
    #pragma unroll
    for (int off = 32; off > 0; off >>= 1) {
        p0 += __shfl_down(p0, off);
        p1 += __shfl_down(p1, off);
        p2 += __shfl_down(p2, off);
        p3 += __shfl_down(p3, off);
    }
    __shared__ float red[4][4];
    int wv = tid >> 6, lane = tid & 63;
    if (lane == 0) { red[wv][0] = p0; red[wv][1] = p1; red[wv][2] = p2; red[wv][3] = p3; }
    __syncthreads();
    if (tid < 4) {
        a_out[b * L_ + tid] = red[0][tid] + red[1][tid] + red[2][tid] + red[3][tid];
    }
}

// ---------------- One-time weight transposes (both in one launch) ----------------
// z=0: W_ih [GR, KX] -> WihT [KX, GR];  z=1: W_hh [GR, R] -> WhhT [R, GR]
__global__ void k_transpose2(const float* __restrict__ Wih, const float* __restrict__ Whh,
                             float* __restrict__ WihT, float* __restrict__ WhhT) {
    const float* in = blockIdx.z ? Whh : Wih;
    float* outp = blockIdx.z ? WhhT : WihT;
    int kdim = blockIdx.z ? R_ : KX_;
    if (blockIdx.x * 32 >= kdim) return;
    __shared__ float tile[32][33];
    int j0 = blockIdx.x * 32;  // k dim
    int i0 = blockIdx.y * 32;  // n dim (GR)
    int tx = threadIdx.x, ty = threadIdx.y;  // 32, 8
    #pragma unroll
    for (int dy = 0; dy < 32; dy += 8) {
        int i = i0 + ty + dy, j = j0 + tx;
        if (j < kdim) tile[ty + dy][tx] = in[(size_t)i * kdim + j];
    }
    __syncthreads();
    #pragma unroll
    for (int dy = 0; dy < 32; dy += 8) {
        int j = j0 + ty + dy, i = i0 + tx;
        if (j < kdim) outp[(size_t)j * GR_ + i] = tile[tx][ty + dy];
    }
}

// ---------------- Fused per-step: pre (bmi head) + GRU cell ----------------
// grid (R/64=8, B/4=32), block 1024 = 16 waves.
// wave w: bb = w>>2 (batch-in-block), q = w&3 (merged-K quarter).
// Pre phase: waves 0..3 each handle one batch (head + xcat build into LDS).
// GEMM phase: wave (bb,q) accumulates quarter q of merged K=616 for 64 outputs; LDS reduce.
__global__ void __launch_bounds__(1024, 1) k_step(
        const float* __restrict__ h, const float* __restrict__ W_reg,
        const float* __restrict__ b_reg, const float* __restrict__ a_vec,
        const float* __restrict__ featEmbed, const float* __restrict__ labelsEmbed,
        const int* __restrict__ mask, const float* __restrict__ emb_table,
        const float* __restrict__ WihT, const float* __restrict__ WhhT,
        const float* __restrict__ b_ih, const float* __restrict__ b_hh,
        int t, float* __restrict__ h_out, float* __restrict__ out) {
    int tid = threadIdx.x;
    int lane = tid & 63;
    int w = tid >> 6;       // 0..15
    int bb = w >> 2;        // 0..3
    int q = w & 3;          // 0..3
    int b = blockIdx.y * 4 + bb;
    int rr = blockIdx.x * 64 + lane;

    __shared__ float xs[4][KX_];          // xcat rows for this block's 4 batches
    __shared__ float red[4][3][64][4];    // [bb][q-1][lane][{r,z,in,hn}]

    // ---- pre phase: waves 0..3 ----
    if (w < 4) {
        int bp = blockIdx.y * 4 + w;
        const float* hb = h + bp * R_;
        float p0 = 0.f, p1 = 0.f, p2 = 0.f, p3 = 0.f;
        #pragma unroll
        for (int r = lane; r < R_; r += 64) {
            float v = hb[r];
            p0 = fmaf(v, W_reg[r], p0);
            p1 = fmaf(v, W_reg[512 + r], p1);
            p2 = fmaf(v, W_reg[1024 + r], p2);
            p3 = fmaf(v, W_reg[1536 + r], p3);
        }
        #pragma unroll
        for (int off = 32; off > 0; off >>= 1) {
            p0 += __shfl_down(p0, off);
            p1 += __shfl_down(p1, off);
            p2 += __shfl_down(p2, off);
            p3 += __shfl_down(p3, off);
        }
        p0 = __shfl(p0, 0); p1 = __shfl(p1, 0); p2 = __shfl(p2, 0); p3 = __shfl(p3, 0);
        float bh[4];
        bh[0] = p0 + b_reg[0] + a_vec[bp * 4 + 0];
        bh[1] = p1 + b_reg[1] + a_vec[bp * 4 + 1];
        bh[2] = p2 + b_reg[2] + a_vec[bp * 4 + 2];
        bh[3] = p3 + b_reg[3] + a_vec[bp * 4 + 3];
        float pr[4];
        #pragma unroll
        for (int l = 0; l < 4; ++l) pr[l] = sigmoidf(bh[l]);
        int best = 0;
        float bv = pr[0];
        #pragma unroll
        for (int l = 1; l < 4; ++l) {
            if (pr[l] > bv) { bv = pr[l]; best = l; }  // first-max, matches np argmax
        }
        int ld = c_remap[best];
        if (blockIdx.x == 0 && lane == 0) {
            out[t * B_ + bp] = (float)best;
            #pragma unroll
            for (int l = 0; l < 4; ++l) {
                out[1024 + (t * B_ + bp) * 4 + l] = pr[l];
                out[5120 + (t * B_ + bp) * 4 + l] = bh[l];
            }
            out[9216 + t * B_ + bp] = (float)ld;
        }
        if (lane < E_) {
            xs[w][lane] = featEmbed[bp * (T_ * E_) + t * E_ + lane];
            int m = mask[bp * T_ + t];
            xs[w][E_ + lane] = m ? labelsEmbed[bp * (T_ * E_) + t * E_ + lane]
                                 : emb_table[ld * E_ + lane];
        }
    }
    __syncthreads();

    // ---- GEMM phase: wave (bb, q), merged K in [q*154, q*154+154) ----
    float ar = 0.f, az = 0.f, ain = 0.f, ahn = 0.f;
    int k0 = q * KQ_, k1 = k0 + KQ_;
    // x segment: merged k in [k0, min(k1, 104))
    int xe = min(k1, KX_);
    #pragma unroll 4
    for (int k = k0; k < xe; ++k) {
        float x = xs[bb][k];
        const float* wp = WihT + (size_t)k * GR_ + rr;
        ar = fmaf(x, wp[0], ar);
        az = fmaf(x, wp[512], az);
        ain = fmaf(x, wp[1024], ain);
    }
    // h segment: h-index in [max(k0,104)-104, k1-104)
    const float* hrow = h + b * R_;
    int hs = max(k0, KX_) - KX_;
    int he = k1 - KX_;
    #pragma unroll 4
    for (int k = hs; k < he; ++k) {
        float hv = hrow[k];
        const float* wp = WhhT + (size_t)k * GR_ + rr;
        ar = fmaf(hv, wp[0], ar);
        az = fmaf(hv, wp[512], az);
        ahn = fmaf(hv, wp[1024], ahn);
    }
    if (q != 0) {
        red[bb][q - 1][lane][0] = ar;
        red[bb][q - 1][lane][1] = az;
        red[bb][q - 1][lane][2] = ain;
        red[bb][q - 1][lane][3] = ahn;
    }
    __syncthreads();
    if (q == 0) {
        #pragma unroll
        for (int j = 0; j < 3; ++j) {
            ar += red[bb][j][lane][0];
            az += red[bb][j][lane][1];
            ain += red[bb][j][lane][2];
            ahn += red[bb][j][lane][3];
        }
        float r = sigmoidf(ar + b_ih[rr] + b_hh[rr]);
        float z = sigmoidf(az + b_ih[rr + 512] + b_hh[rr + 512]);
        float n = tanhf(ain + b_ih[rr + 1024] + r * (ahn + b_hh[rr + 1024]));
        h_out[b * R_ + rr] = (1.0f - z) * n + z * hrow[rr];
    }
}

extern "C" void kernel_launch(void* const* d_in, const int* in_sizes, int n_in,
                              void* d_out, int out_size, void* d_ws, size_t ws_size,
                              hipStream_t stream) {
    const float* featEmbed   = (const float*)d_in[0];
    const float* labelsEmbed = (const float*)d_in[1];
    const float* enc         = (const float*)d_in[2];
    const float* h_n         = (const float*)d_in[3];
    const int*   mask        = (const int*)d_in[4];
    const int*   enc_len     = (const int*)d_in[5];
    const float* emb_table   = (const float*)d_in[6];
    const float* W_fc        = (const float*)d_in[7];
    const float* W_reg       = (const float*)d_in[8];
    const float* b_reg       = (const float*)d_in[9];
    const float* W_ih        = (const float*)d_in[10];
    const float* W_hh        = (const float*)d_in[11];
    const float* b_ih        = (const float*)d_in[12];
    const float* b_hh        = (const float*)d_in[13];
    float* out = (float*)d_out;

    // workspace layout (floats); total ~2.14M floats = ~8.6 MB
    float* ws      = (float*)d_ws;
    float* partial = ws;                          // B*NCHUNK*R = 1048576
    float* WihT    = partial + B_ * NCHUNK * R_;  // KX*GR = 159744
    float* WhhT    = WihT + KX_ * GR_;            // R*GR  = 786432
    float* h0      = WhhT + R_ * GR_;             // B*R   = 65536
    float* h1      = h0 + B_ * R_;                // B*R   = 65536
    float* a_vec   = h1 + B_ * R_;                // B*L   = 512

    k_transpose2<<<dim3(16, GR_ / 32, 2), dim3(32, 8), 0, stream>>>(W_ih, W_hh, WihT, WhhT);
    k_maxpool<<<dim3(NCHUNK, B_), 128, 0, stream>>>(enc, enc_len, (float4*)partial);
    k_pool_a<<<B_, 256, 0, stream>>>(partial, W_fc, a_vec);

    const float* hcur = h_n;
    for (int t = 0; t < T_; ++t) {
        float* hnext = (t & 1) ? h1 : h0;
        k_step<<<dim3(R_ / 64, B_ / 4), 1024, 0, stream>>>(
            hcur, W_reg, b_reg, a_vec, featEmbed, labelsEmbed, mask, emb_table,
            WihT, WhhT, b_ih, b_hh, t, hnext, out);
        hcur = hnext;
    }
}